// Round 20
// baseline (76.758 us; speedup 1.0000x reference)
//
#include <hip/hip_runtime.h>
#include <math.h>

#define Bb 64
#define Ss 512
#define Hh 768
#define Ll 9
#define CCH 32      // CRF chunks per batch
#define TCH 16      // steps per chunk
#define NROWS (Bb * Ss)       // 32768
#define NTILES (NROWS / 16)   // 2048 tiles; 2 waves per tile (K-split)
#define KSTEPS 24             // 768 / 32
#define KHALF 12              // K-steps per wave
#define EST 12                // exp-emissions stride (floats)
#define EMIS_SMEM 28672       // bpack 24576 + combine 4096
#define CRF_SMEM  44800

typedef __attribute__((ext_vector_type(8))) short short8;   // 8 x bf16
typedef __attribute__((ext_vector_type(4))) float f32x4;

__device__ __forceinline__ ushort f2bf(float f) {           // RNE (W only)
    unsigned u = __float_as_uint(f);
    return (ushort)((u + 0x7FFFu + ((u >> 16) & 1u)) >> 16);
}
__device__ __forceinline__ float uniform_sgpr(float x) {    // wave-uniform -> SGPR
    return __int_as_float(__builtin_amdgcn_readfirstlane(__float_as_int(x)));
}

// ---------------- K1: MFMA emissions -> EXP(emissions), stride-12 (unchanged) ----------------
__global__ __launch_bounds__(512, 2) void k_emis(
    const float* __restrict__ hs, const float* __restrict__ W,
    const float* __restrict__ bvec, const float* __restrict__ cw,
    float* __restrict__ ee2, float* __restrict__ out)
{
    extern __shared__ char smem[];
    uint4* bpack = (uint4*)smem;                 // [KSTEPS][64]
    float* comb  = (float*)(smem + 24576);       // [4][4*64]
    const int tid = threadIdx.x;

    if (blockIdx.x == 0 && tid == 0) out[0] = 0.f;

    const int wid  = tid >> 6;
    const int tl   = wid >> 1;
    const int half = wid & 1;
    const int lane = tid & 63;
    const int col = lane & 15, kg = lane >> 4;
    const int gtile = blockIdx.x * 4 + tl;
    const int row0 = gtile * 16;
    const float* ap = hs + (size_t)(row0 + col) * Hh + kg * 8 + half * (KHALF * 32);

    float4 c0[4], c1[4];
#pragma unroll
    for (int p = 0; p < 4; ++p) {
        c0[p] = *(const float4*)(ap + p * 32);
        c1[p] = *(const float4*)(ap + p * 32 + 4);
    }

    for (int slot = tid; slot < KSTEPS * 64; slot += 512) {
        const int s = slot >> 6, l = slot & 63;
        const int bcol = l & 15, bkg = l >> 4;
        ushort h[8];
#pragma unroll
        for (int j = 0; j < 8; ++j) {
            const int k = s * 32 + bkg * 8 + j;
            h[j] = (bcol < Ll) ? f2bf(W[k * Ll + bcol]) : (ushort)0;
        }
        uint4 u;
        u.x = (unsigned)h[0] | ((unsigned)h[1] << 16);
        u.y = (unsigned)h[2] | ((unsigned)h[3] << 16);
        u.z = (unsigned)h[4] | ((unsigned)h[5] << 16);
        u.w = (unsigned)h[6] | ((unsigned)h[7] << 16);
        bpack[slot] = u;
    }
    __syncthreads();

    f32x4 acc = {0.f, 0.f, 0.f, 0.f};
#pragma unroll
    for (int t = 0; t < KHALF; ++t) {
        const int sl = t & 3;
        const float4 a0 = c0[sl], a1 = c1[sl];
        if (t + 4 < KHALF) {
            c0[sl] = *(const float4*)(ap + (t + 4) * 32);
            c1[sl] = *(const float4*)(ap + (t + 4) * 32 + 4);
        }
        const unsigned x0 = __float_as_uint(a0.x), x1 = __float_as_uint(a0.y);
        const unsigned x2 = __float_as_uint(a0.z), x3 = __float_as_uint(a0.w);
        const unsigned y0 = __float_as_uint(a1.x), y1 = __float_as_uint(a1.y);
        const unsigned y2 = __float_as_uint(a1.z), y3 = __float_as_uint(a1.w);
        uint4 au;
        au.x = (x1 & 0xFFFF0000u) | (x0 >> 16);
        au.y = (x3 & 0xFFFF0000u) | (x2 >> 16);
        au.z = (y1 & 0xFFFF0000u) | (y0 >> 16);
        au.w = (y3 & 0xFFFF0000u) | (y2 >> 16);
        const short8 a = __builtin_bit_cast(short8, au);
        const short8 b = __builtin_bit_cast(short8,
                                            bpack[(half * KHALF + t) * 64 + lane]);
        acc = __builtin_amdgcn_mfma_f32_16x16x32_bf16(a, b, acc, 0, 0, 0);
    }

    if (half == 1) {
#pragma unroll
        for (int j = 0; j < 4; ++j)
            comb[(tl * 4 + j) * 64 + lane] = acc[j];
    }
    __syncthreads();
    if (half == 0) {
#pragma unroll
        for (int j = 0; j < 4; ++j)
            acc[j] += comb[(tl * 4 + j) * 64 + lane];
        if (col < Ll) {
            const float cwv = cw[col], bv = bvec[col];
#pragma unroll
            for (int j = 0; j < 4; ++j)
                ee2[(size_t)(row0 + kg * 4 + j) * EST + col] =
                    __expf((acc[j] + bv) * cwv);
        }
    }
}

// ---------------- K2: CRF (R19 body + weight param) ----------------
__global__ __launch_bounds__(384) void k_crf(
    const float* __restrict__ ee2, const int* __restrict__ labels,
    const int* __restrict__ attn, const float* __restrict__ trans,
    const float* __restrict__ startt, const float* __restrict__ endt,
    float* __restrict__ out, float invw)
{
    extern __shared__ char smem[];
    float* ee_s    = (float*)smem;                 //     0..24576 (512*12 f)
    int*   mkt_s   = (int*)(smem + 24576);         // 512 int
    float* trans_s = (float*)(smem + 26624);       // 81 f
    float* et_s    = (float*)(smem + 26948);       // 81 f
    float* rm0     = (float*)(smem + 27272);       // 32*9
    float* er0     = (float*)(smem + 28424);       // 32*81
    float* rm1     = (float*)(smem + 38792);       // 16*9
    float* er1     = (float*)(smem + 39368);       // 16*81
    float* num_s   = (float*)(smem + 44552);       // 1 f

    const int b   = blockIdx.x;
    const int tid = threadIdx.x;

    {
        const float4* src = (const float4*)(ee2 + (size_t)b * Ss * EST);
        float4* dst = (float4*)ee_s;
#pragma unroll
        for (int i = 0; i < 4; ++i) dst[tid + i * 384] = src[tid + i * 384];
    }
    for (int t = tid; t < Ss; t += 384) {
        const int lab = labels[b * Ss + t];
        const int att = attn[b * Ss + t];
        const int tag = (lab == -100) ? 0 : lab;
        const int mk  = ((lab != -100) && (att == 1)) ? 1 : 0;
        mkt_s[t] = tag | (mk << 4);
    }
    if (tid < Ll * Ll) {
        const float tv = trans[tid];
        trans_s[tid] = tv;
        et_s[tid] = __expf(tv);
    }
    __syncthreads();

    // ---- chunk scan: tid < 288; linear recurrence from LDS ----
    if (tid < CCH * Ll) {
        const int i = tid % Ll;
        const int c = tid / Ll;
        float et[Ll][Ll];
#pragma unroll
        for (int l = 0; l < Ll; ++l)
#pragma unroll
            for (int k = 0; k < Ll; ++k)
                et[l][k] = uniform_sgpr(et_s[l * Ll + k]);

        const float* ep = ee_s + (c * TCH) * EST;
        float u[Ll];
#pragma unroll
        for (int l = 0; l < Ll; ++l) u[l] = (l == i) ? 1.f : 0.f;
        float rlog = 0.f;

#pragma unroll
        for (int s = 0; s < TCH; ++s) {
            const int t = c * TCH + s;
            const int mv = mkt_s[t];
            if ((c != 0 || s > 0) && (mv >> 4)) {
                const float4 q0 = *(const float4*)(ep + s * EST);
                const float4 q1 = *(const float4*)(ep + s * EST + 4);
                const float  e8 = ep[s * EST + 8];
                float e[Ll];
                e[0] = q0.x; e[1] = q0.y; e[2] = q0.z; e[3] = q0.w;
                e[4] = q1.x; e[5] = q1.y; e[6] = q1.z; e[7] = q1.w;
                e[8] = e8;
                float nu[Ll];
#pragma unroll
                for (int k = 0; k < Ll; ++k) {
                    float sacc = 0.f;
#pragma unroll
                    for (int l = 0; l < Ll; ++l) sacc = fmaf(u[l], et[l][k], sacc);
                    nu[k] = sacc * e[k];
                }
#pragma unroll
                for (int l = 0; l < Ll; ++l) u[l] = nu[l];
            }
            if ((s & 3) == 3) {
                float mx = u[0];
#pragma unroll
                for (int l = 1; l < Ll; ++l) mx = fmaxf(mx, u[l]);
                rlog += __logf(mx);
                const float r = 1.f / mx;
#pragma unroll
                for (int l = 0; l < Ll; ++l) u[l] *= r;
            }
        }
        float mx = u[0];
#pragma unroll
        for (int l = 1; l < Ll; ++l) mx = fmaxf(mx, u[l]);
        rm0[c * Ll + i] = rlog + __logf(mx);
        const float r = 1.f / mx;
#pragma unroll
        for (int l = 0; l < Ll; ++l)
            er0[(c * Ll + i) * Ll + l] = u[l] * r;
    }

    // ---- numerator: wave 5 (tid 320..383), product trick, LDS reads ----
    if (tid >= 320) {
        const int lane = tid - 320;
        float psum = 0.f, pr0 = 1.f, pr1 = 1.f;
        int pcnt = 0;
#pragma unroll
        for (int j = 0; j < 8; ++j) {
            const int t = lane + j * 64;
            const int mv  = mkt_s[t];
            const int tag = mv & 15;
            const bool mk = (mv >> 4) || (t == 0);
            if (t >= 1 && (mv >> 4)) {
                const int tagp = mkt_s[t - 1] & 15;
                psum += trans_s[tagp * Ll + tag];
                const float ev = ee_s[t * EST + tag];
                if (j < 4) pr0 *= ev; else pr1 *= ev;
            }
            pcnt += mk ? 1 : 0;
        }
        psum += __logf(pr0) + __logf(pr1);
#pragma unroll
        for (int off = 32; off; off >>= 1) {
            psum += __shfl_xor(psum, off);
            pcnt += __shfl_xor(pcnt, off);
        }
        if (lane == 0) {
            const int tag0 = mkt_s[0] & 15;
            const int tagL = mkt_s[pcnt - 1] & 15;
            num_s[0] = startt[tag0] + __logf(ee_s[tag0]) + psum + endt[tagL];
        }
    }

    // ---- tree compose: 5 levels ----
    float *rs = rm0, *es = er0, *rd = rm1, *ed = er1;
    int nodes = 16;
    for (int lev = 0; lev < 5; ++lev) {
        __syncthreads();
        if (tid < nodes * Ll) {
            const int node = tid / Ll, i = tid % Ll;
            const float* rmA = rs + (2 * node) * Ll;
            const float* erA = es + (size_t)(2 * node) * Ll * Ll;
            const float* rmB = rs + (2 * node + 1) * Ll;
            const float* erB = es + (size_t)(2 * node + 1) * Ll * Ll;
            float MB = rmB[0];
#pragma unroll
            for (int l = 1; l < Ll; ++l) MB = fmaxf(MB, rmB[l]);
            float w[Ll];
#pragma unroll
            for (int l = 0; l < Ll; ++l)
                w[l] = erA[i * Ll + l] * __expf(rmB[l] - MB);
            float p[Ll];
#pragma unroll
            for (int k = 0; k < Ll; ++k) {
                float s = 0.f;
#pragma unroll
                for (int l = 0; l < Ll; ++l) s = fmaf(w[l], erB[l * Ll + k], s);
                p[k] = s;
            }
            float pm = p[0];
#pragma unroll
            for (int k = 1; k < Ll; ++k) pm = fmaxf(pm, p[k]);
            pm = fmaxf(pm, 1e-30f);
            rd[node * Ll + i] = rmA[i] + MB + __logf(pm);
            const float r = 1.f / pm;
#pragma unroll
            for (int k = 0; k < Ll; ++k)
                ed[node * Ll * Ll + i * Ll + k] = p[k] * r;
        }
        float* t1 = rs; rs = rd; rd = t1;
        float* t2 = es; es = ed; ed = t2;
        nodes >>= 1;
    }
    __syncthreads();

    // ---- final: v0 * T * end, one thread ----
    if (tid == 0) {
        const float* rmT = rs;
        const float* erT = es;
        float g[Ll];
        float MG = -1e30f;
#pragma unroll
        for (int l = 0; l < Ll; ++l) {
            g[l] = startt[l] + __logf(ee_s[l]) + rmT[l];
            MG = fmaxf(MG, g[l]);
        }
        float tot = 0.f;
#pragma unroll
        for (int k = 0; k < Ll; ++k) {
            float vk = 0.f;
#pragma unroll
            for (int i = 0; i < Ll; ++i)
                vk = fmaf(__expf(g[i] - MG), erT[i * Ll + k], vk);
            tot += vk * __expf(endt[k]);
        }
        const float logz = MG + __logf(tot);
        atomicAdd(out, -(num_s[0] - logz) * invw);
    }
}

extern "C" void kernel_launch(void* const* d_in, const int* in_sizes, int n_in,
                              void* d_out, int out_size, void* d_ws, size_t ws_size,
                              hipStream_t stream)
{
    const float* hs     = (const float*)d_in[0];
    const float* W      = (const float*)d_in[1];
    const float* bvec   = (const float*)d_in[2];
    const float* cw     = (const float*)d_in[3];
    const float* startt = (const float*)d_in[4];
    const float* endt   = (const float*)d_in[5];
    const float* trans  = (const float*)d_in[6];
    const int*   labels = (const int*)d_in[7];
    const int*   attn   = (const int*)d_in[8];
    float* out = (float*)d_out;
    float* ee2 = (float*)d_ws;   // exp-emissions, 32768 * 12 floats

    // MEASUREMENT ROUND: k_crf launched 3x, each adding 1/3 of the mean.
    // delta vs R19 = 2 * (k_crf + node_overhead). Output = exact mean.
    const float invw = 1.f / (3.f * Bb);
    hipLaunchKernelGGL(k_emis, dim3(NTILES / 4), dim3(512), EMIS_SMEM, stream,
                       hs, W, bvec, cw, ee2, out);
    hipLaunchKernelGGL(k_crf, dim3(Bb), dim3(384), CRF_SMEM, stream,
                       ee2, labels, attn, trans, startt, endt, out, invw);
    hipLaunchKernelGGL(k_crf, dim3(Bb), dim3(384), CRF_SMEM, stream,
                       ee2, labels, attn, trans, startt, endt, out, invw);
    hipLaunchKernelGGL(k_crf, dim3(Bb), dim3(384), CRF_SMEM, stream,
                       ee2, labels, attn, trans, startt, endt, out, invw);
}

// Round 21
// 44.632 us; speedup vs baseline: 1.7198x; 1.7198x over previous
//
#include <hip/hip_runtime.h>
#include <math.h>

#define Bb 64
#define Ss 512
#define Hh 768
#define Ll 9
#define CCH 32      // CRF chunks per batch
#define TCH 16      // steps per chunk
#define NROWS (Bb * Ss)       // 32768
#define NTILES (NROWS / 16)   // 2048 tiles; 2 waves per tile (K-split)
#define KSTEPS 24             // 768 / 32
#define KHALF 12              // K-steps per wave
#define EST 12                // exp-emissions stride (floats)
#define EMIS_SMEM 28672       // bpack 24576 + combine 4096
#define CRF_SMEM  44800

typedef __attribute__((ext_vector_type(8))) short short8;   // 8 x bf16
typedef __attribute__((ext_vector_type(4))) float f32x4;

__device__ __forceinline__ ushort f2bf(float f) {           // RNE (W only)
    unsigned u = __float_as_uint(f);
    return (ushort)((u + 0x7FFFu + ((u >> 16) & 1u)) >> 16);
}
__device__ __forceinline__ float uniform_sgpr(float x) {    // wave-uniform -> SGPR
    return __int_as_float(__builtin_amdgcn_readfirstlane(__float_as_int(x)));
}

// ---------------- K1: MFMA emissions -> EXP(emissions), stride-12 (unchanged) ----------------
__global__ __launch_bounds__(512, 2) void k_emis(
    const float* __restrict__ hs, const float* __restrict__ W,
    const float* __restrict__ bvec, const float* __restrict__ cw,
    float* __restrict__ ee2)
{
    extern __shared__ char smem[];
    uint4* bpack = (uint4*)smem;                 // [KSTEPS][64]
    float* comb  = (float*)(smem + 24576);       // [4][4*64]
    const int tid = threadIdx.x;

    const int wid  = tid >> 6;
    const int tl   = wid >> 1;
    const int half = wid & 1;
    const int lane = tid & 63;
    const int col = lane & 15, kg = lane >> 4;
    const int gtile = blockIdx.x * 4 + tl;
    const int row0 = gtile * 16;
    const float* ap = hs + (size_t)(row0 + col) * Hh + kg * 8 + half * (KHALF * 32);

    float4 c0[4], c1[4];
#pragma unroll
    for (int p = 0; p < 4; ++p) {
        c0[p] = *(const float4*)(ap + p * 32);
        c1[p] = *(const float4*)(ap + p * 32 + 4);
    }

    for (int slot = tid; slot < KSTEPS * 64; slot += 512) {
        const int s = slot >> 6, l = slot & 63;
        const int bcol = l & 15, bkg = l >> 4;
        ushort h[8];
#pragma unroll
        for (int j = 0; j < 8; ++j) {
            const int k = s * 32 + bkg * 8 + j;
            h[j] = (bcol < Ll) ? f2bf(W[k * Ll + bcol]) : (ushort)0;
        }
        uint4 u;
        u.x = (unsigned)h[0] | ((unsigned)h[1] << 16);
        u.y = (unsigned)h[2] | ((unsigned)h[3] << 16);
        u.z = (unsigned)h[4] | ((unsigned)h[5] << 16);
        u.w = (unsigned)h[6] | ((unsigned)h[7] << 16);
        bpack[slot] = u;
    }
    __syncthreads();

    f32x4 acc = {0.f, 0.f, 0.f, 0.f};
#pragma unroll
    for (int t = 0; t < KHALF; ++t) {
        const int sl = t & 3;
        const float4 a0 = c0[sl], a1 = c1[sl];
        if (t + 4 < KHALF) {
            c0[sl] = *(const float4*)(ap + (t + 4) * 32);
            c1[sl] = *(const float4*)(ap + (t + 4) * 32 + 4);
        }
        const unsigned x0 = __float_as_uint(a0.x), x1 = __float_as_uint(a0.y);
        const unsigned x2 = __float_as_uint(a0.z), x3 = __float_as_uint(a0.w);
        const unsigned y0 = __float_as_uint(a1.x), y1 = __float_as_uint(a1.y);
        const unsigned y2 = __float_as_uint(a1.z), y3 = __float_as_uint(a1.w);
        uint4 au;
        au.x = (x1 & 0xFFFF0000u) | (x0 >> 16);
        au.y = (x3 & 0xFFFF0000u) | (x2 >> 16);
        au.z = (y1 & 0xFFFF0000u) | (y0 >> 16);
        au.w = (y3 & 0xFFFF0000u) | (y2 >> 16);
        const short8 a = __builtin_bit_cast(short8, au);
        const short8 b = __builtin_bit_cast(short8,
                                            bpack[(half * KHALF + t) * 64 + lane]);
        acc = __builtin_amdgcn_mfma_f32_16x16x32_bf16(a, b, acc, 0, 0, 0);
    }

    if (half == 1) {
#pragma unroll
        for (int j = 0; j < 4; ++j)
            comb[(tl * 4 + j) * 64 + lane] = acc[j];
    }
    __syncthreads();
    if (half == 0) {
#pragma unroll
        for (int j = 0; j < 4; ++j)
            acc[j] += comb[(tl * 4 + j) * 64 + lane];
        if (col < Ll) {
            const float cwv = cw[col], bv = bvec[col];
#pragma unroll
            for (int j = 0; j < 4; ++j)
                ee2[(size_t)(row0 + kg * 4 + j) * EST + col] =
                    __expf((acc[j] + bv) * cwv);
        }
    }
}

// ---------------- K2: CRF — NO atomics; writes llh[b] to ws ----------------
__global__ __launch_bounds__(384) void k_crf(
    const float* __restrict__ ee2, const int* __restrict__ labels,
    const int* __restrict__ attn, const float* __restrict__ trans,
    const float* __restrict__ startt, const float* __restrict__ endt,
    float* __restrict__ llh)
{
    extern __shared__ char smem[];
    float* ee_s    = (float*)smem;                 //     0..24576 (512*12 f)
    int*   mkt_s   = (int*)(smem + 24576);         // 512 int
    float* trans_s = (float*)(smem + 26624);       // 81 f
    float* et_s    = (float*)(smem + 26948);       // 81 f
    float* rm0     = (float*)(smem + 27272);       // 32*9
    float* er0     = (float*)(smem + 28424);       // 32*81
    float* rm1     = (float*)(smem + 38792);       // 16*9
    float* er1     = (float*)(smem + 39368);       // 16*81
    float* num_s   = (float*)(smem + 44552);       // 1 f

    const int b   = blockIdx.x;
    const int tid = threadIdx.x;

    {
        const float4* src = (const float4*)(ee2 + (size_t)b * Ss * EST);
        float4* dst = (float4*)ee_s;
#pragma unroll
        for (int i = 0; i < 4; ++i) dst[tid + i * 384] = src[tid + i * 384];
    }
    for (int t = tid; t < Ss; t += 384) {
        const int lab = labels[b * Ss + t];
        const int att = attn[b * Ss + t];
        const int tag = (lab == -100) ? 0 : lab;
        const int mk  = ((lab != -100) && (att == 1)) ? 1 : 0;
        mkt_s[t] = tag | (mk << 4);
    }
    if (tid < Ll * Ll) {
        const float tv = trans[tid];
        trans_s[tid] = tv;
        et_s[tid] = __expf(tv);
    }
    __syncthreads();

    // ---- chunk scan: tid < 288; linear recurrence from LDS ----
    if (tid < CCH * Ll) {
        const int i = tid % Ll;
        const int c = tid / Ll;
        float et[Ll][Ll];
#pragma unroll
        for (int l = 0; l < Ll; ++l)
#pragma unroll
            for (int k = 0; k < Ll; ++k)
                et[l][k] = uniform_sgpr(et_s[l * Ll + k]);

        const float* ep = ee_s + (c * TCH) * EST;
        float u[Ll];
#pragma unroll
        for (int l = 0; l < Ll; ++l) u[l] = (l == i) ? 1.f : 0.f;
        float rlog = 0.f;

#pragma unroll
        for (int s = 0; s < TCH; ++s) {
            const int t = c * TCH + s;
            const int mv = mkt_s[t];
            if ((c != 0 || s > 0) && (mv >> 4)) {
                const float4 q0 = *(const float4*)(ep + s * EST);
                const float4 q1 = *(const float4*)(ep + s * EST + 4);
                const float  e8 = ep[s * EST + 8];
                float e[Ll];
                e[0] = q0.x; e[1] = q0.y; e[2] = q0.z; e[3] = q0.w;
                e[4] = q1.x; e[5] = q1.y; e[6] = q1.z; e[7] = q1.w;
                e[8] = e8;
                float nu[Ll];
#pragma unroll
                for (int k = 0; k < Ll; ++k) {
                    float sacc = 0.f;
#pragma unroll
                    for (int l = 0; l < Ll; ++l) sacc = fmaf(u[l], et[l][k], sacc);
                    nu[k] = sacc * e[k];
                }
#pragma unroll
                for (int l = 0; l < Ll; ++l) u[l] = nu[l];
            }
            if ((s & 3) == 3) {
                float mx = u[0];
#pragma unroll
                for (int l = 1; l < Ll; ++l) mx = fmaxf(mx, u[l]);
                rlog += __logf(mx);
                const float r = 1.f / mx;
#pragma unroll
                for (int l = 0; l < Ll; ++l) u[l] *= r;
            }
        }
        float mx = u[0];
#pragma unroll
        for (int l = 1; l < Ll; ++l) mx = fmaxf(mx, u[l]);
        rm0[c * Ll + i] = rlog + __logf(mx);
        const float r = 1.f / mx;
#pragma unroll
        for (int l = 0; l < Ll; ++l)
            er0[(c * Ll + i) * Ll + l] = u[l] * r;
    }

    // ---- numerator: wave 5 (tid 320..383), product trick, LDS reads ----
    if (tid >= 320) {
        const int lane = tid - 320;
        float psum = 0.f, pr0 = 1.f, pr1 = 1.f;
        int pcnt = 0;
#pragma unroll
        for (int j = 0; j < 8; ++j) {
            const int t = lane + j * 64;
            const int mv  = mkt_s[t];
            const int tag = mv & 15;
            const bool mk = (mv >> 4) || (t == 0);
            if (t >= 1 && (mv >> 4)) {
                const int tagp = mkt_s[t - 1] & 15;
                psum += trans_s[tagp * Ll + tag];
                const float ev = ee_s[t * EST + tag];
                if (j < 4) pr0 *= ev; else pr1 *= ev;
            }
            pcnt += mk ? 1 : 0;
        }
        psum += __logf(pr0) + __logf(pr1);
#pragma unroll
        for (int off = 32; off; off >>= 1) {
            psum += __shfl_xor(psum, off);
            pcnt += __shfl_xor(pcnt, off);
        }
        if (lane == 0) {
            const int tag0 = mkt_s[0] & 15;
            const int tagL = mkt_s[pcnt - 1] & 15;
            num_s[0] = startt[tag0] + __logf(ee_s[tag0]) + psum + endt[tagL];
        }
    }

    // ---- tree compose: 5 levels ----
    float *rs = rm0, *es = er0, *rd = rm1, *ed = er1;
    int nodes = 16;
    for (int lev = 0; lev < 5; ++lev) {
        __syncthreads();
        if (tid < nodes * Ll) {
            const int node = tid / Ll, i = tid % Ll;
            const float* rmA = rs + (2 * node) * Ll;
            const float* erA = es + (size_t)(2 * node) * Ll * Ll;
            const float* rmB = rs + (2 * node + 1) * Ll;
            const float* erB = es + (size_t)(2 * node + 1) * Ll * Ll;
            float MB = rmB[0];
#pragma unroll
            for (int l = 1; l < Ll; ++l) MB = fmaxf(MB, rmB[l]);
            float w[Ll];
#pragma unroll
            for (int l = 0; l < Ll; ++l)
                w[l] = erA[i * Ll + l] * __expf(rmB[l] - MB);
            float p[Ll];
#pragma unroll
            for (int k = 0; k < Ll; ++k) {
                float s = 0.f;
#pragma unroll
                for (int l = 0; l < Ll; ++l) s = fmaf(w[l], erB[l * Ll + k], s);
                p[k] = s;
            }
            float pm = p[0];
#pragma unroll
            for (int k = 1; k < Ll; ++k) pm = fmaxf(pm, p[k]);
            pm = fmaxf(pm, 1e-30f);
            rd[node * Ll + i] = rmA[i] + MB + __logf(pm);
            const float r = 1.f / pm;
#pragma unroll
            for (int k = 0; k < Ll; ++k)
                ed[node * Ll * Ll + i * Ll + k] = p[k] * r;
        }
        float* t1 = rs; rs = rd; rd = t1;
        float* t2 = es; es = ed; ed = t2;
        nodes >>= 1;
    }
    __syncthreads();

    // ---- final: v0 * T * end, one thread; plain store (NO atomic) ----
    if (tid == 0) {
        const float* rmT = rs;
        const float* erT = es;
        float g[Ll];
        float MG = -1e30f;
#pragma unroll
        for (int l = 0; l < Ll; ++l) {
            g[l] = startt[l] + __logf(ee_s[l]) + rmT[l];
            MG = fmaxf(MG, g[l]);
        }
        float tot = 0.f;
#pragma unroll
        for (int k = 0; k < Ll; ++k) {
            float vk = 0.f;
#pragma unroll
            for (int i = 0; i < Ll; ++i)
                vk = fmaf(__expf(g[i] - MG), erT[i * Ll + k], vk);
            tot += vk * __expf(endt[k]);
        }
        const float logz = MG + __logf(tot);
        llh[b] = num_s[0] - logz;
    }
}

// ---------------- K3: final reduce (64 lanes, no atomics) ----------------
__global__ __launch_bounds__(64) void k_fin(const float* __restrict__ llh,
                                            float* __restrict__ out)
{
    const int lane = threadIdx.x;
    float v = llh[lane];
#pragma unroll
    for (int off = 32; off; off >>= 1) v += __shfl_xor(v, off);
    if (lane == 0) out[0] = -v * (1.f / Bb);
}

extern "C" void kernel_launch(void* const* d_in, const int* in_sizes, int n_in,
                              void* d_out, int out_size, void* d_ws, size_t ws_size,
                              hipStream_t stream)
{
    const float* hs     = (const float*)d_in[0];
    const float* W      = (const float*)d_in[1];
    const float* bvec   = (const float*)d_in[2];
    const float* cw     = (const float*)d_in[3];
    const float* startt = (const float*)d_in[4];
    const float* endt   = (const float*)d_in[5];
    const float* trans  = (const float*)d_in[6];
    const int*   labels = (const int*)d_in[7];
    const int*   attn   = (const int*)d_in[8];
    float* out = (float*)d_out;
    float* ee2 = (float*)d_ws;                        // 32768*12 floats
    float* llh = ee2 + (size_t)NROWS * EST;           // 64 floats

    hipLaunchKernelGGL(k_emis, dim3(NTILES / 4), dim3(512), EMIS_SMEM, stream,
                       hs, W, bvec, cw, ee2);
    hipLaunchKernelGGL(k_crf, dim3(Bb), dim3(384), CRF_SMEM, stream,
                       ee2, labels, attn, trans, startt, endt, llh);
    hipLaunchKernelGGL(k_fin, dim3(1), dim3(64), 0, stream, llh, out);
}

// Round 22
// 39.232 us; speedup vs baseline: 1.9565x; 1.1376x over previous
//
#include <hip/hip_runtime.h>
#include <math.h>

#define Bb 64
#define Ss 512
#define Hh 768
#define Ll 9
#define CCH 32      // CRF chunks per batch
#define TCH 16      // steps per chunk
#define NROWS (Bb * Ss)       // 32768
#define NTILES (NROWS / 16)   // 2048 tiles; 2 waves per tile (K-split)
#define KSTEPS 24             // 768 / 32
#define KHALF 12              // K-steps per wave
#define EST 12                // exp-emissions stride (floats)
#define EMIS_SMEM 28672       // bpack 24576 + combine 4096
#define CRF_SMEM  44800

typedef __attribute__((ext_vector_type(8))) short short8;   // 8 x bf16
typedef __attribute__((ext_vector_type(4))) float f32x4;

__device__ __forceinline__ ushort f2bf(float f) {           // RNE (W only)
    unsigned u = __float_as_uint(f);
    return (ushort)((u + 0x7FFFu + ((u >> 16) & 1u)) >> 16);
}

// ---------------- K1: MFMA emissions -> EXP(emissions), stride-12 (unchanged) ----------------
__global__ __launch_bounds__(512, 2) void k_emis(
    const float* __restrict__ hs, const float* __restrict__ W,
    const float* __restrict__ bvec, const float* __restrict__ cw,
    float* __restrict__ ee2, float* __restrict__ out)
{
    extern __shared__ char smem[];
    uint4* bpack = (uint4*)smem;                 // [KSTEPS][64]
    float* comb  = (float*)(smem + 24576);       // [4][4*64]
    const int tid = threadIdx.x;

    if (blockIdx.x == 0 && tid == 0) out[0] = 0.f;

    const int wid  = tid >> 6;
    const int tl   = wid >> 1;
    const int half = wid & 1;
    const int lane = tid & 63;
    const int col = lane & 15, kg = lane >> 4;
    const int gtile = blockIdx.x * 4 + tl;
    const int row0 = gtile * 16;
    const float* ap = hs + (size_t)(row0 + col) * Hh + kg * 8 + half * (KHALF * 32);

    float4 c0[4], c1[4];
#pragma unroll
    for (int p = 0; p < 4; ++p) {
        c0[p] = *(const float4*)(ap + p * 32);
        c1[p] = *(const float4*)(ap + p * 32 + 4);
    }

    for (int slot = tid; slot < KSTEPS * 64; slot += 512) {
        const int s = slot >> 6, l = slot & 63;
        const int bcol = l & 15, bkg = l >> 4;
        ushort h[8];
#pragma unroll
        for (int j = 0; j < 8; ++j) {
            const int k = s * 32 + bkg * 8 + j;
            h[j] = (bcol < Ll) ? f2bf(W[k * Ll + bcol]) : (ushort)0;
        }
        uint4 u;
        u.x = (unsigned)h[0] | ((unsigned)h[1] << 16);
        u.y = (unsigned)h[2] | ((unsigned)h[3] << 16);
        u.z = (unsigned)h[4] | ((unsigned)h[5] << 16);
        u.w = (unsigned)h[6] | ((unsigned)h[7] << 16);
        bpack[slot] = u;
    }
    __syncthreads();

    f32x4 acc = {0.f, 0.f, 0.f, 0.f};
#pragma unroll
    for (int t = 0; t < KHALF; ++t) {
        const int sl = t & 3;
        const float4 a0 = c0[sl], a1 = c1[sl];
        if (t + 4 < KHALF) {
            c0[sl] = *(const float4*)(ap + (t + 4) * 32);
            c1[sl] = *(const float4*)(ap + (t + 4) * 32 + 4);
        }
        const unsigned x0 = __float_as_uint(a0.x), x1 = __float_as_uint(a0.y);
        const unsigned x2 = __float_as_uint(a0.z), x3 = __float_as_uint(a0.w);
        const unsigned y0 = __float_as_uint(a1.x), y1 = __float_as_uint(a1.y);
        const unsigned y2 = __float_as_uint(a1.z), y3 = __float_as_uint(a1.w);
        uint4 au;
        au.x = (x1 & 0xFFFF0000u) | (x0 >> 16);
        au.y = (x3 & 0xFFFF0000u) | (x2 >> 16);
        au.z = (y1 & 0xFFFF0000u) | (y0 >> 16);
        au.w = (y3 & 0xFFFF0000u) | (y2 >> 16);
        const short8 a = __builtin_bit_cast(short8, au);
        const short8 b = __builtin_bit_cast(short8,
                                            bpack[(half * KHALF + t) * 64 + lane]);
        acc = __builtin_amdgcn_mfma_f32_16x16x32_bf16(a, b, acc, 0, 0, 0);
    }

    if (half == 1) {
#pragma unroll
        for (int j = 0; j < 4; ++j)
            comb[(tl * 4 + j) * 64 + lane] = acc[j];
    }
    __syncthreads();
    if (half == 0) {
#pragma unroll
        for (int j = 0; j < 4; ++j)
            acc[j] += comb[(tl * 4 + j) * 64 + lane];
        if (col < Ll) {
            const float cwv = cw[col], bv = bvec[col];
#pragma unroll
            for (int j = 0; j < 4; ++j)
                ee2[(size_t)(row0 + kg * 4 + j) * EST + col] =
                    __expf((acc[j] + bv) * cwv);
        }
    }
}

// ---------------- K2: CRF — et PINNED in VGPRs (anti-sinking), atomic epilogue ----------------
__global__ __launch_bounds__(384, 1) void k_crf(
    const float* __restrict__ ee2, const int* __restrict__ labels,
    const int* __restrict__ attn, const float* __restrict__ trans,
    const float* __restrict__ startt, const float* __restrict__ endt,
    float* __restrict__ out)
{
    extern __shared__ char smem[];
    float* ee_s    = (float*)smem;                 //     0..24576 (512*12 f)
    int*   mkt_s   = (int*)(smem + 24576);         // 512 int
    float* trans_s = (float*)(smem + 26624);       // 81 f
    float* et_s    = (float*)(smem + 26948);       // 81 f
    float* rm0     = (float*)(smem + 27272);       // 32*9
    float* er0     = (float*)(smem + 28424);       // 32*81
    float* rm1     = (float*)(smem + 38792);       // 16*9
    float* er1     = (float*)(smem + 39368);       // 16*81
    float* num_s   = (float*)(smem + 44552);       // 1 f

    const int b   = blockIdx.x;
    const int tid = threadIdx.x;

    {
        const float4* src = (const float4*)(ee2 + (size_t)b * Ss * EST);
        float4* dst = (float4*)ee_s;
#pragma unroll
        for (int i = 0; i < 4; ++i) dst[tid + i * 384] = src[tid + i * 384];
    }
    for (int t = tid; t < Ss; t += 384) {
        const int lab = labels[b * Ss + t];
        const int att = attn[b * Ss + t];
        const int tag = (lab == -100) ? 0 : lab;
        const int mk  = ((lab != -100) && (att == 1)) ? 1 : 0;
        mkt_s[t] = tag | (mk << 4);
    }
    if (tid < Ll * Ll) {
        const float tv = trans[tid];
        trans_s[tid] = tv;
        et_s[tid] = __expf(tv);
    }
    __syncthreads();

    // ---- chunk scan: tid < 288; linear recurrence from LDS ----
    if (tid < CCH * Ll) {
        const int i = tid % Ll;
        const int c = tid / Ll;
        // load exp(trans) into VGPRs and PIN: opaque asm blocks rematerialization/
        // re-reading from LDS inside the unrolled loop (the R6/R7 failure mode).
        float et[Ll][Ll];
#pragma unroll
        for (int l = 0; l < Ll; ++l)
#pragma unroll
            for (int k = 0; k < Ll; ++k) {
                float v = et_s[l * Ll + k];
                asm volatile("" : "+v"(v));
                et[l][k] = v;
            }

        const float* ep = ee_s + (c * TCH) * EST;
        float u[Ll];
#pragma unroll
        for (int l = 0; l < Ll; ++l) u[l] = (l == i) ? 1.f : 0.f;
        float rlog = 0.f;

#pragma unroll
        for (int s = 0; s < TCH; ++s) {
            const int t = c * TCH + s;
            const int mv = mkt_s[t];
            if ((c != 0 || s > 0) && (mv >> 4)) {
                const float4 q0 = *(const float4*)(ep + s * EST);
                const float4 q1 = *(const float4*)(ep + s * EST + 4);
                const float  e8 = ep[s * EST + 8];
                float e[Ll];
                e[0] = q0.x; e[1] = q0.y; e[2] = q0.z; e[3] = q0.w;
                e[4] = q1.x; e[5] = q1.y; e[6] = q1.z; e[7] = q1.w;
                e[8] = e8;
                float nu[Ll];
#pragma unroll
                for (int k = 0; k < Ll; ++k) {
                    float sacc = 0.f;
#pragma unroll
                    for (int l = 0; l < Ll; ++l) sacc = fmaf(u[l], et[l][k], sacc);
                    nu[k] = sacc * e[k];
                }
#pragma unroll
                for (int l = 0; l < Ll; ++l) u[l] = nu[l];
            }
            if ((s & 3) == 3) {
                float mx = u[0];
#pragma unroll
                for (int l = 1; l < Ll; ++l) mx = fmaxf(mx, u[l]);
                rlog += __logf(mx);
                const float r = 1.f / mx;
#pragma unroll
                for (int l = 0; l < Ll; ++l) u[l] *= r;
            }
        }
        float mx = u[0];
#pragma unroll
        for (int l = 1; l < Ll; ++l) mx = fmaxf(mx, u[l]);
        rm0[c * Ll + i] = rlog + __logf(mx);
        const float r = 1.f / mx;
#pragma unroll
        for (int l = 0; l < Ll; ++l)
            er0[(c * Ll + i) * Ll + l] = u[l] * r;
    }

    // ---- numerator: wave 5 (tid 320..383), product trick, LDS reads ----
    if (tid >= 320) {
        const int lane = tid - 320;
        float psum = 0.f, pr0 = 1.f, pr1 = 1.f;
        int pcnt = 0;
#pragma unroll
        for (int j = 0; j < 8; ++j) {
            const int t = lane + j * 64;
            const int mv  = mkt_s[t];
            const int tag = mv & 15;
            const bool mk = (mv >> 4) || (t == 0);
            if (t >= 1 && (mv >> 4)) {
                const int tagp = mkt_s[t - 1] & 15;
                psum += trans_s[tagp * Ll + tag];
                const float ev = ee_s[t * EST + tag];
                if (j < 4) pr0 *= ev; else pr1 *= ev;
            }
            pcnt += mk ? 1 : 0;
        }
        psum += __logf(pr0) + __logf(pr1);
#pragma unroll
        for (int off = 32; off; off >>= 1) {
            psum += __shfl_xor(psum, off);
            pcnt += __shfl_xor(pcnt, off);
        }
        if (lane == 0) {
            const int tag0 = mkt_s[0] & 15;
            const int tagL = mkt_s[pcnt - 1] & 15;
            num_s[0] = startt[tag0] + __logf(ee_s[tag0]) + psum + endt[tagL];
        }
    }

    // ---- tree compose: 5 levels ----
    float *rs = rm0, *es = er0, *rd = rm1, *ed = er1;
    int nodes = 16;
    for (int lev = 0; lev < 5; ++lev) {
        __syncthreads();
        if (tid < nodes * Ll) {
            const int node = tid / Ll, i = tid % Ll;
            const float* rmA = rs + (2 * node) * Ll;
            const float* erA = es + (size_t)(2 * node) * Ll * Ll;
            const float* rmB = rs + (2 * node + 1) * Ll;
            const float* erB = es + (size_t)(2 * node + 1) * Ll * Ll;
            float MB = rmB[0];
#pragma unroll
            for (int l = 1; l < Ll; ++l) MB = fmaxf(MB, rmB[l]);
            float w[Ll];
#pragma unroll
            for (int l = 0; l < Ll; ++l)
                w[l] = erA[i * Ll + l] * __expf(rmB[l] - MB);
            float p[Ll];
#pragma unroll
            for (int k = 0; k < Ll; ++k) {
                float s = 0.f;
#pragma unroll
                for (int l = 0; l < Ll; ++l) s = fmaf(w[l], erB[l * Ll + k], s);
                p[k] = s;
            }
            float pm = p[0];
#pragma unroll
            for (int k = 1; k < Ll; ++k) pm = fmaxf(pm, p[k]);
            pm = fmaxf(pm, 1e-30f);
            rd[node * Ll + i] = rmA[i] + MB + __logf(pm);
            const float r = 1.f / pm;
#pragma unroll
            for (int k = 0; k < Ll; ++k)
                ed[node * Ll * Ll + i * Ll + k] = p[k] * r;
        }
        float* t1 = rs; rs = rd; rd = t1;
        float* t2 = es; es = ed; ed = t2;
        nodes >>= 1;
    }
    __syncthreads();

    // ---- final: v0 * T * end, one thread; atomic (cheaper than a 3rd node, R21) ----
    if (tid == 0) {
        const float* rmT = rs;
        const float* erT = es;
        float g[Ll];
        float MG = -1e30f;
#pragma unroll
        for (int l = 0; l < Ll; ++l) {
            g[l] = startt[l] + __logf(ee_s[l]) + rmT[l];
            MG = fmaxf(MG, g[l]);
        }
        float tot = 0.f;
#pragma unroll
        for (int k = 0; k < Ll; ++k) {
            float vk = 0.f;
#pragma unroll
            for (int i = 0; i < Ll; ++i)
                vk = fmaf(__expf(g[i] - MG), erT[i * Ll + k], vk);
            tot += vk * __expf(endt[k]);
        }
        const float logz = MG + __logf(tot);
        atomicAdd(out, -(num_s[0] - logz) * (1.f / Bb));
    }
}

extern "C" void kernel_launch(void* const* d_in, const int* in_sizes, int n_in,
                              void* d_out, int out_size, void* d_ws, size_t ws_size,
                              hipStream_t stream)
{
    const float* hs     = (const float*)d_in[0];
    const float* W      = (const float*)d_in[1];
    const float* bvec   = (const float*)d_in[2];
    const float* cw     = (const float*)d_in[3];
    const float* startt = (const float*)d_in[4];
    const float* endt   = (const float*)d_in[5];
    const float* trans  = (const float*)d_in[6];
    const int*   labels = (const int*)d_in[7];
    const int*   attn   = (const int*)d_in[8];
    float* out = (float*)d_out;
    float* ee2 = (float*)d_ws;   // exp-emissions, 32768 * 12 floats

    hipLaunchKernelGGL(k_emis, dim3(NTILES / 4), dim3(512), EMIS_SMEM, stream,
                       hs, W, bvec, cw, ee2, out);
    hipLaunchKernelGGL(k_crf, dim3(Bb), dim3(384), CRF_SMEM, stream,
                       ee2, labels, attn, trans, startt, endt, out);
}

// Round 23
// 38.703 us; speedup vs baseline: 1.9833x; 1.0137x over previous
//
#include <hip/hip_runtime.h>
#include <math.h>

#define Bb 64
#define Ss 512
#define Hh 768
#define Ll 9
#define CCH 32      // CRF chunks per batch
#define TCH 16      // steps per chunk
#define NROWS (Bb * Ss)       // 32768
#define NTILES (NROWS / 16)   // 2048 tiles; 2 waves per tile (K-split)
#define KSTEPS 24             // 768 / 32
#define KHALF 12              // K-steps per wave
#define EST 12                // exp-emissions stride (floats)
#define EMIS_SMEM 28672       // bpack 24576 + combine 4096
#define CRF_SMEM  20480

typedef __attribute__((ext_vector_type(8))) short short8;   // 8 x bf16
typedef __attribute__((ext_vector_type(4))) float f32x4;

__device__ __forceinline__ ushort f2bf(float f) {           // RNE (W only)
    unsigned u = __float_as_uint(f);
    return (ushort)((u + 0x7FFFu + ((u >> 16) & 1u)) >> 16);
}

// ---------------- K1: MFMA emissions -> EXP(emissions), stride-12 (unchanged) ----------------
__global__ __launch_bounds__(512, 2) void k_emis(
    const float* __restrict__ hs, const float* __restrict__ W,
    const float* __restrict__ bvec, const float* __restrict__ cw,
    float* __restrict__ ee2, float* __restrict__ out)
{
    extern __shared__ char smem[];
    uint4* bpack = (uint4*)smem;                 // [KSTEPS][64]
    float* comb  = (float*)(smem + 24576);       // [4][4*64]
    const int tid = threadIdx.x;

    if (blockIdx.x == 0 && tid == 0) out[0] = 0.f;

    const int wid  = tid >> 6;
    const int tl   = wid >> 1;
    const int half = wid & 1;
    const int lane = tid & 63;
    const int col = lane & 15, kg = lane >> 4;
    const int gtile = blockIdx.x * 4 + tl;
    const int row0 = gtile * 16;
    const float* ap = hs + (size_t)(row0 + col) * Hh + kg * 8 + half * (KHALF * 32);

    float4 c0[4], c1[4];
#pragma unroll
    for (int p = 0; p < 4; ++p) {
        c0[p] = *(const float4*)(ap + p * 32);
        c1[p] = *(const float4*)(ap + p * 32 + 4);
    }

    for (int slot = tid; slot < KSTEPS * 64; slot += 512) {
        const int s = slot >> 6, l = slot & 63;
        const int bcol = l & 15, bkg = l >> 4;
        ushort h[8];
#pragma unroll
        for (int j = 0; j < 8; ++j) {
            const int k = s * 32 + bkg * 8 + j;
            h[j] = (bcol < Ll) ? f2bf(W[k * Ll + bcol]) : (ushort)0;
        }
        uint4 u;
        u.x = (unsigned)h[0] | ((unsigned)h[1] << 16);
        u.y = (unsigned)h[2] | ((unsigned)h[3] << 16);
        u.z = (unsigned)h[4] | ((unsigned)h[5] << 16);
        u.w = (unsigned)h[6] | ((unsigned)h[7] << 16);
        bpack[slot] = u;
    }
    __syncthreads();

    f32x4 acc = {0.f, 0.f, 0.f, 0.f};
#pragma unroll
    for (int t = 0; t < KHALF; ++t) {
        const int sl = t & 3;
        const float4 a0 = c0[sl], a1 = c1[sl];
        if (t + 4 < KHALF) {
            c0[sl] = *(const float4*)(ap + (t + 4) * 32);
            c1[sl] = *(const float4*)(ap + (t + 4) * 32 + 4);
        }
        const unsigned x0 = __float_as_uint(a0.x), x1 = __float_as_uint(a0.y);
        const unsigned x2 = __float_as_uint(a0.z), x3 = __float_as_uint(a0.w);
        const unsigned y0 = __float_as_uint(a1.x), y1 = __float_as_uint(a1.y);
        const unsigned y2 = __float_as_uint(a1.z), y3 = __float_as_uint(a1.w);
        uint4 au;
        au.x = (x1 & 0xFFFF0000u) | (x0 >> 16);
        au.y = (x3 & 0xFFFF0000u) | (x2 >> 16);
        au.z = (y1 & 0xFFFF0000u) | (y0 >> 16);
        au.w = (y3 & 0xFFFF0000u) | (y2 >> 16);
        const short8 a = __builtin_bit_cast(short8, au);
        const short8 b = __builtin_bit_cast(short8,
                                            bpack[(half * KHALF + t) * 64 + lane]);
        acc = __builtin_amdgcn_mfma_f32_16x16x32_bf16(a, b, acc, 0, 0, 0);
    }

    if (half == 1) {
#pragma unroll
        for (int j = 0; j < 4; ++j)
            comb[(tl * 4 + j) * 64 + lane] = acc[j];
    }
    __syncthreads();
    if (half == 0) {
#pragma unroll
        for (int j = 0; j < 4; ++j)
            acc[j] += comb[(tl * 4 + j) * 64 + lane];
        if (col < Ll) {
            const float cwv = cw[col], bv = bvec[col];
#pragma unroll
            for (int j = 0; j < 4; ++j)
                ee2[(size_t)(row0 + kg * 4 + j) * EST + col] =
                    __expf((acc[j] + bv) * cwv);
        }
    }
}

// ---------------- K2: CRF — no ee stage; scan/numerator stream from global ----------------
__global__ __launch_bounds__(384, 1) void k_crf(
    const float* __restrict__ ee2, const int* __restrict__ labels,
    const int* __restrict__ attn, const float* __restrict__ trans,
    const float* __restrict__ startt, const float* __restrict__ endt,
    float* __restrict__ out)
{
    extern __shared__ char smem[];
    int*   mkt_s   = (int*)smem;                   //     0..2048
    float* trans_s = (float*)(smem + 2048);        // 81 f
    float* et_s    = (float*)(smem + 2372);        // 81 f
    float* rm0     = (float*)(smem + 2696);        // 32*9
    float* er0     = (float*)(smem + 3848);        // 32*81
    float* rm1     = (float*)(smem + 14216);       // 16*9
    float* er1     = (float*)(smem + 14792);       // 16*81
    float* num_s   = (float*)(smem + 19976);       // 1 f

    const int b   = blockIdx.x;
    const int tid = threadIdx.x;

    // ---- tiny stage: masks/tags + transitions (no ee stage) ----
    for (int t = tid; t < Ss; t += 384) {
        const int lab = labels[b * Ss + t];
        const int att = attn[b * Ss + t];
        const int tag = (lab == -100) ? 0 : lab;
        const int mk  = ((lab != -100) && (att == 1)) ? 1 : 0;
        mkt_s[t] = tag | (mk << 4);
    }
    if (tid < Ll * Ll) {
        const float tv = trans[tid];
        trans_s[tid] = tv;
        et_s[tid] = __expf(tv);
    }
    __syncthreads();

    // ---- chunk scan: tid < 288; linear recurrence, ee from GLOBAL (ping-pong) ----
    if (tid < CCH * Ll) {
        const int i = tid % Ll;
        const int c = tid / Ll;
        // exp(trans) pinned in VGPRs (anti-sinking, proven R22)
        float et[Ll][Ll];
#pragma unroll
        for (int l = 0; l < Ll; ++l)
#pragma unroll
            for (int k = 0; k < Ll; ++k) {
                float v = et_s[l * Ll + k];
                asm volatile("" : "+v"(v));
                et[l][k] = v;
            }

        const float* ep = ee2 + (size_t)(b * Ss + c * TCH) * EST;
        float4 p0[2], p1[2]; float p2[2];
        p0[0] = *(const float4*)ep;
        p1[0] = *(const float4*)(ep + 4);
        p2[0] = ep[8];

        float u[Ll];
#pragma unroll
        for (int l = 0; l < Ll; ++l) u[l] = (l == i) ? 1.f : 0.f;
        float rlog = 0.f;

#pragma unroll
        for (int s = 0; s < TCH; ++s) {
            const int cur = s & 1;
            if (s + 1 < TCH) {
                const float* np = ep + (s + 1) * EST;
                p0[cur ^ 1] = *(const float4*)np;
                p1[cur ^ 1] = *(const float4*)(np + 4);
                p2[cur ^ 1] = np[8];
            }
            const int t = c * TCH + s;
            const int mv = mkt_s[t];
            if ((c != 0 || s > 0) && (mv >> 4)) {
                float e[Ll];
                e[0] = p0[cur].x; e[1] = p0[cur].y; e[2] = p0[cur].z; e[3] = p0[cur].w;
                e[4] = p1[cur].x; e[5] = p1[cur].y; e[6] = p1[cur].z; e[7] = p1[cur].w;
                e[8] = p2[cur];
                float nu[Ll];
#pragma unroll
                for (int k = 0; k < Ll; ++k) {
                    float sacc = 0.f;
#pragma unroll
                    for (int l = 0; l < Ll; ++l) sacc = fmaf(u[l], et[l][k], sacc);
                    nu[k] = sacc * e[k];
                }
#pragma unroll
                for (int l = 0; l < Ll; ++l) u[l] = nu[l];
            }
            if ((s & 3) == 3) {
                float mx = u[0];
#pragma unroll
                for (int l = 1; l < Ll; ++l) mx = fmaxf(mx, u[l]);
                rlog += __logf(mx);
                const float r = 1.f / mx;
#pragma unroll
                for (int l = 0; l < Ll; ++l) u[l] *= r;
            }
        }
        float mx = u[0];
#pragma unroll
        for (int l = 1; l < Ll; ++l) mx = fmaxf(mx, u[l]);
        rm0[c * Ll + i] = rlog + __logf(mx);
        const float r = 1.f / mx;
#pragma unroll
        for (int l = 0; l < Ll; ++l)
            er0[(c * Ll + i) * Ll + l] = u[l] * r;
    }

    // ---- numerator: wave 5 (tid 320..383), product trick, GLOBAL reads ----
    if (tid >= 320) {
        const int lane = tid - 320;
        float psum = 0.f, pr0 = 1.f, pr1 = 1.f;
        int pcnt = 0;
#pragma unroll
        for (int j = 0; j < 8; ++j) {
            const int t = lane + j * 64;
            const int mv  = mkt_s[t];
            const int tag = mv & 15;
            const bool mk = (mv >> 4) || (t == 0);
            if (t >= 1 && (mv >> 4)) {
                const int tagp = mkt_s[t - 1] & 15;
                psum += trans_s[tagp * Ll + tag];
                const float ev = ee2[(size_t)(b * Ss + t) * EST + tag];
                if (j < 4) pr0 *= ev; else pr1 *= ev;
            }
            pcnt += mk ? 1 : 0;
        }
        psum += __logf(pr0) + __logf(pr1);
#pragma unroll
        for (int off = 32; off; off >>= 1) {
            psum += __shfl_xor(psum, off);
            pcnt += __shfl_xor(pcnt, off);
        }
        if (lane == 0) {
            const int tag0 = mkt_s[0] & 15;
            const int tagL = mkt_s[pcnt - 1] & 15;
            num_s[0] = startt[tag0] + __logf(ee2[(size_t)(b * Ss) * EST + tag0])
                       + psum + endt[tagL];
        }
    }

    // ---- tree compose: 5 levels of pairwise scaled matrix products ----
    float *rs = rm0, *es = er0, *rd = rm1, *ed = er1;
    int nodes = 16;
    for (int lev = 0; lev < 5; ++lev) {
        __syncthreads();
        if (tid < nodes * Ll) {
            const int node = tid / Ll, i = tid % Ll;
            const float* rmA = rs + (2 * node) * Ll;
            const float* erA = es + (size_t)(2 * node) * Ll * Ll;
            const float* rmB = rs + (2 * node + 1) * Ll;
            const float* erB = es + (size_t)(2 * node + 1) * Ll * Ll;
            float MB = rmB[0];
#pragma unroll
            for (int l = 1; l < Ll; ++l) MB = fmaxf(MB, rmB[l]);
            float w[Ll];
#pragma unroll
            for (int l = 0; l < Ll; ++l)
                w[l] = erA[i * Ll + l] * __expf(rmB[l] - MB);
            float p[Ll];
#pragma unroll
            for (int k = 0; k < Ll; ++k) {
                float s = 0.f;
#pragma unroll
                for (int l = 0; l < Ll; ++l) s = fmaf(w[l], erB[l * Ll + k], s);
                p[k] = s;
            }
            float pm = p[0];
#pragma unroll
            for (int k = 1; k < Ll; ++k) pm = fmaxf(pm, p[k]);
            pm = fmaxf(pm, 1e-30f);
            rd[node * Ll + i] = rmA[i] + MB + __logf(pm);
            const float r = 1.f / pm;
#pragma unroll
            for (int k = 0; k < Ll; ++k)
                ed[node * Ll * Ll + i * Ll + k] = p[k] * r;
        }
        float* t1 = rs; rs = rd; rd = t1;
        float* t2 = es; es = ed; ed = t2;
        nodes >>= 1;
    }
    __syncthreads();

    // ---- final: v0 * T * end, one thread; atomic epilogue ----
    if (tid == 0) {
        const float* rmT = rs;
        const float* erT = es;
        float g[Ll];
        float MG = -1e30f;
#pragma unroll
        for (int l = 0; l < Ll; ++l) {
            g[l] = startt[l] + __logf(ee2[(size_t)(b * Ss) * EST + l]) + rmT[l];
            MG = fmaxf(MG, g[l]);
        }
        float tot = 0.f;
#pragma unroll
        for (int k = 0; k < Ll; ++k) {
            float vk = 0.f;
#pragma unroll
            for (int i = 0; i < Ll; ++i)
                vk = fmaf(__expf(g[i] - MG), erT[i * Ll + k], vk);
            tot += vk * __expf(endt[k]);
        }
        const float logz = MG + __logf(tot);
        atomicAdd(out, -(num_s[0] - logz) * (1.f / Bb));
    }
}

extern "C" void kernel_launch(void* const* d_in, const int* in_sizes, int n_in,
                              void* d_out, int out_size, void* d_ws, size_t ws_size,
                              hipStream_t stream)
{
    const float* hs     = (const float*)d_in[0];
    const float* W      = (const float*)d_in[1];
    const float* bvec   = (const float*)d_in[2];
    const float* cw     = (const float*)d_in[3];
    const float* startt = (const float*)d_in[4];
    const float* endt   = (const float*)d_in[5];
    const float* trans  = (const float*)d_in[6];
    const int*   labels = (const int*)d_in[7];
    const int*   attn   = (const int*)d_in[8];
    float* out = (float*)d_out;
    float* ee2 = (float*)d_ws;   // exp-emissions, 32768 * 12 floats

    hipLaunchKernelGGL(k_emis, dim3(NTILES / 4), dim3(512), EMIS_SMEM, stream,
                       hs, W, bvec, cw, ee2, out);
    hipLaunchKernelGGL(k_crf, dim3(Bb), dim3(384), CRF_SMEM, stream,
                       ee2, labels, attn, trans, startt, endt, out);
}